// Round 5
// baseline (53.556 us; speedup 1.0000x reference)
//
#include <hip/hip_runtime.h>
#include <math.h>

// NormalLoss: for each template vertex (M=6890), take the K=15 scan points
// (N=20000) with LARGEST distance, among them pick the min-angle normal
// match, loss = mean ||sv[sel]-tv||.
//
// Round-11: keep R4 sort pipeline (memset ghist -> rank via global-atomic
// ranks -> scatter, all provably cheap: no per-thread loops). Rework knn's
// candidate machinery, which cross-round elimination (R2/R3/R4 mid-pipeline
// swaps at constant ~48-50 us total vs R0/R1's 30.5) pins as the ~35-40 us
// hot spot:
//  * batched top-16 maintenance: per active chunk, bitonic-sort the 64
//    candidates desc by (d2,-idx), then bitonic k-select merge
//    new_i = max_order(A_i, B_{15-i}) + 4-stage clean. Flat ~160 instrs
//    per chunk vs ~10 x #candidates serialized (the old while(mb) loop
//    with loop-carried thr dependency). Serial path kept for chunks with
//    <=6 candidates. Select provably yields the top-16 multiset under the
//    same total order -> lanes 0..14 stay the exact top-15 -> output
//    bit-identical.
//  * restored pts-load-before-break + rmax prefetch (lost in the octant
//    rewrite; round-5 ledger: scalar bound load must overlap vector
//    point loads).
//  * octant bound unchanged (exact Cauchy-Schwarz): max d^2 over octant
//    suffix = r^2+|tv|^2+2 r g_o, g_o = opposed-component energy; top
//    shell r=+inf; *1.00001 fp-safe margin; bootstrap in argmax-g octant.
//  * reduce: 1-block sum (no atomics on out; 1723-same-address atomics
//    remain banned per round-5 ledger).

constexpr int K = 15;
constexpr int RBUCK = 256;         // radial shells per octant (0.125-wide |p|^2)
constexpr int NBUCK2 = 8 * RBUCK;  // total buckets
constexpr int WAVES = 4;           // waves (=vertices) per block in main kernel

__device__ __forceinline__ int rbucket_of(float k2) {
    int b = (int)(k2 * 8.0f);
    b = b > (RBUCK - 1) ? (RBUCK - 1) : b;
    return (RBUCK - 1) - b;        // 0 = largest |p| shell
}
__device__ __forceinline__ int octant_of(float x, float y, float z) {
    return (x < 0.0f ? 1 : 0) | (y < 0.0f ? 2 : 0) | (z < 0.0f ? 4 : 0);
}

// full-wave bitonic sort, descending by (v desc, idx asc) total order
__device__ __forceinline__ void sort64_desc(int lane, float& v, int& idx) {
#pragma unroll
    for (int k = 2; k <= 64; k <<= 1) {
#pragma unroll
        for (int j = k >> 1; j > 0; j >>= 1) {
            float ov = __shfl_xor(v, j);
            int   oi = __shfl_xor(idx, j);
            bool up    = ((lane & k) == 0);   // descending segment
            bool lower = ((lane & j) == 0);
            bool mine  = (v > ov) || (v == ov && idx < oi);
            bool keep  = lower ? (up ? mine : !mine) : (up ? !mine : mine);
            if (!keep) { v = ov; idx = oi; }
        }
    }
}

// rank[i] = within-bucket arrival order; packed (rank<<11)|bucket (rank
// < 2^15, bucket < 2^11 -> 26 bits, positive).
__global__ __launch_bounds__(256) void rank_kernel(
    const float* __restrict__ sv, int* __restrict__ ghist,
    int* __restrict__ pb, int N)
{
    int i = blockIdx.x * 256 + threadIdx.x;
    if (i < N) {
        float x = sv[3*i], y = sv[3*i+1], z = sv[3*i+2];
        int b = (octant_of(x, y, z) << 8) |
                rbucket_of(fmaf(x, x, fmaf(y, y, z*z)));
        int r = atomicAdd(&ghist[b], 1);      // device-scope global atomic
        pb[i] = (r << 11) | b;
    }
}

// Each block: ghist (2 int4/thread, one load-group) -> local KS scan ->
// scatter own 256 points at start[b]+rank. Block 0 also tabulates rmax +
// octStartG from the same scan.
__global__ __launch_bounds__(256) void scatter_kernel(
    const float* __restrict__ sv,
    const int*   __restrict__ ghist,     // [2048] bucket totals
    const int*   __restrict__ pb,        // [N] packed (rank<<11)|bucket
    float4*      __restrict__ sorted,    // [N] out: (x,y,z,bitcast(origIdx))
    float*       __restrict__ rmax,      // [8*nb+8] out: radial bound per (oct,chunk)
    int*         __restrict__ octStartG, // [9] out: octant starts (+N)
    int N, int nb)
{
    __shared__ int startSh[NBUCK2];
    __shared__ int tsum[256];
    const int t = threadIdx.x;

    // thread t owns buckets [t*8, t*8+8): two int4 loads, ONE group
    const int4* gh4 = (const int4*)ghist;
    int4 a = gh4[t * 2];
    int4 c = gh4[t * 2 + 1];
    int tot[8] = {a.x, a.y, a.z, a.w, c.x, c.y, c.z, c.w};
    int tsumv = 0;
#pragma unroll
    for (int j = 0; j < 8; ++j) tsumv += tot[j];
    tsum[t] = tsumv;
    __syncthreads();
    // Kogge-Stone inclusive scan over per-thread sums
    for (int d = 1; d < 256; d <<= 1) {
        int u = (t >= d) ? tsum[t - d] : 0;
        __syncthreads();
        tsum[t] += u;
        __syncthreads();
    }
    int running = tsum[t] - tsumv;      // exclusive start of this thread's range
#pragma unroll
    for (int j = 0; j < 8; ++j) {
        startSh[t*8 + j] = running;
        running += tot[j];
    }
    __syncthreads();

    if (blockIdx.x == 0) {
        if (t < 8) octStartG[t] = startSh[t << 8];
        if (t == 8) octStartG[8] = N;
        // rmax[o][k]: radial |p| upper bound for octant-o positions >= oS+64k.
        // Shell found by binary search over startSh; bound = shell upper edge.
        // Top shell (rb==0, |p|^2 may exceed clamp) -> +inf (exact-safe).
        for (int o = 0; o < 8; ++o) {
            int oS = startSh[o << 8];
            int oE = (o < 7) ? startSh[(o + 1) << 8] : N;
            for (int k = t; oS + (k << 6) < oE; k += 256) {
                int pos = oS + (k << 6);
                int lo = 0, hi = RBUCK - 1;
                while (lo < hi) {
                    int mid = (lo + hi + 1) >> 1;
                    if (startSh[(o << 8) + mid] <= pos) lo = mid; else hi = mid - 1;
                }
                rmax[o*nb + k] = (lo == 0) ? 3.0e38f
                                           : sqrtf((float)(RBUCK - lo) * 0.125f);
            }
        }
    }

    int i = blockIdx.x * 256 + t;
    if (i < N) {
        float x = sv[3*i], y = sv[3*i+1], z = sv[3*i+2];
        int pbv = pb[i];
        int b   = pbv & (NBUCK2 - 1);
        int r   = pbv >> 11;
        sorted[startSh[b] + r] = make_float4(x, y, z, __int_as_float(i));
    }
}

template<bool SORTED>
__global__ __launch_bounds__(WAVES * 64) void knn_loss_kernel(
    const float4* __restrict__ pts,    // octant/radial-sorted points (SORTED)
    const float*  __restrict__ rmax,   // [8*nbo+8] radial bound per (oct,chunk)
    const int*    __restrict__ octStartG, // [9]
    const float*  __restrict__ sv,     // [N,3] original scan vertices
    const float*  __restrict__ tv,     // [M,3]
    const float*  __restrict__ sn,     // [N,3]
    const float*  __restrict__ tn,     // [M,3]
    float* __restrict__ partial,       // [gridDim.x] per-block sums
    int N, int M, float invM, int nbo)
{
    __shared__ float bsum[WAVES];
    const int lane = threadIdx.x & 63;
    const int w    = threadIdx.x >> 6;
    const int m    = blockIdx.x * WAVES + w;
    const bool valid = (m < M);

    float contrib = 0.0f;
    if (valid) {
        const float tvx = tv[3*m], tvy = tv[3*m+1], tvz = tv[3*m+2];
        const float tx2 = tvx*tvx, ty2 = tvy*tvy, tz2 = tvz*tvz;
        const float t2  = tx2 + ty2 + tz2;

        // per-octant opposition energy: contribution of component i to g^2
        // if octant sign is negative (cxn) / positive (cxp).
        const float cxn = (tvx > 0.0f) ? tx2 : 0.0f;
        const float cxp = (tvx < 0.0f) ? tx2 : 0.0f;
        const float cyn = (tvy > 0.0f) ? ty2 : 0.0f;
        const float cyp = (tvy < 0.0f) ? ty2 : 0.0f;
        const float czn = (tvz > 0.0f) ? tz2 : 0.0f;
        const float czp = (tvz < 0.0f) ? tz2 : 0.0f;
        auto g2v = [&](int o) {
            return ((o & 1) ? cxn : cxp) + ((o & 2) ? cyn : cyp)
                 + ((o & 4) ? czn : czp);
        };

        int ob = 0; float bg = 0.0f;
        int prefS = 0; float prefR0 = 0.0f;
        if (SORTED) {
            // most-opposed octant = argmax g^2
            bg = g2v(0);
#pragma unroll
            for (int o = 1; o < 8; ++o) {
                float g2o = g2v(o);
                if (g2o > bg) { bg = g2o; ob = o; }
            }
            // octant starts (9) and chunk-0 radial bounds fetched once into
            // lanes, redistributed via shfl
            if (lane < 9) prefS = octStartG[lane];
            if (lane < 8) prefR0 = rmax[lane * nbo];
        }

        // ---- bootstrap: bitonic-sort 64 points desc by (d2, -idx) ----
        float v; int idx;
        int oS = 0, oE = N;
        {
            int l; bool hasB;
            float px, py, pz;
            if (SORTED) {
                oS = __shfl(prefS, ob); oE = __shfl(prefS, ob + 1);
                l = oS + lane; hasB = l < oE;
                float4 q = pts[hasB ? l : 0];
                px = q.x; py = q.y; pz = q.z; idx = __float_as_int(q.w);
            } else {
                l = lane; hasB = l < N;
                int g = hasB ? l : 0;
                px = sv[3*g]; py = sv[3*g+1]; pz = sv[3*g+2]; idx = l;
            }
            float dx = px - tvx, dy = py - tvy, dz = pz - tvz;
            v = fmaf(dx, dx, fmaf(dy, dy, dz * dz));
            if (!hasB) { v = -1.0f; idx = 0x7FFFFFFF; }
        }
        sort64_desc(lane, v, idx);
        // maintain top-16 in lanes 0..15 (sorted desc); lanes 0..14 are the
        // exact top-15 at all times; thr = 15th (lane 14)
        float eV = (lane < 16) ? v : -1.0f;
        int   eI = (lane < 16) ? idx : 0x7FFFFFFF;
        float thr = __shfl(v, 14);

        // candidate machinery: serial insert for sparse chunks, bitonic
        // top-16 merge for dense ones (flat cost, no loop-carried thr chain)
        auto process_chunk = [&](float d2, int oi2, bool has) {
            unsigned long long mb = __ballot(has && (d2 >= thr));
            if (!mb) return;
            int cnt = __popcll(mb);
            if (cnt <= 6) {
                while (mb) {
                    int src = __ffsll(mb) - 1;
                    mb &= mb - 1;
                    float cv = __shfl(d2, src);
                    int   ci = __shfl(oi2, src);
                    unsigned long long bb =
                        __ballot((eV > cv) || (eV == cv && eI < ci)) & 0xFFFFull;
                    int p = __popcll(bb);
                    if (p < 16) {   // wave-uniform
                        float uv = __shfl_up(eV, 1);
                        int   ui = __shfl_up(eI, 1);
                        if (lane < 16) {
                            if (lane == p)      { eV = cv; eI = ci; }
                            else if (lane > p)  { eV = uv; eI = ui; }
                        }
                        thr = __shfl(eV, 14);
                        if (mb) mb &= __ballot(d2 >= thr);
                    }
                }
            } else {
                // sort whole chunk desc; invalid lanes already sentinel
                float bv = has ? d2 : -1.0f;
                int   bi2 = has ? oi2 : 0x7FFFFFFF;
                sort64_desc(lane, bv, bi2);
                // bitonic k-select: new_i = max_order(A_i, B_{15-i});
                // exact top-16 multiset of A ∪ B, bitonic -> 4-stage clean
                float bsel = __shfl(bv, 15 - (lane & 15));
                int   bsi  = __shfl(bi2, 15 - (lane & 15));
                bool takeA = (eV > bsel) || (eV == bsel && eI < bsi);
                float cv = takeA ? eV : bsel;
                int   ci = takeA ? eI  : bsi;
                if (lane >= 16) { cv = -1.0f; ci = 0x7FFFFFFF; }
#pragma unroll
                for (int j = 8; j > 0; j >>= 1) {
                    float ov = __shfl_xor(cv, j);
                    int   oi = __shfl_xor(ci, j);
                    bool mine = (cv > ov) || (cv == ov && ci < oi);
                    bool keep = ((lane & j) == 0) ? mine : !mine;
                    if (!keep) { cv = ov; ci = oi; }
                }
                eV = cv; eI = ci;
                thr = __shfl(eV, 14);
            }
        };

        if (SORTED) {
            // per-octant scan with exact directional bound; point load and
            // next-bound prefetch issue BEFORE the break check (overlap)
            auto scan_octant = [&](int o, int s, int e, int kStart,
                                   float rIn, float g) {
                float r = rIn;
                for (int k = kStart; ; ++k) {
                    int pos = s + (k << 6);
                    if (pos >= e) break;
                    int i = pos + lane;
                    bool has = i < e;
                    float4 q = pts[has ? i : pos];       // issue early
                    float rn = rmax[o*nbo + k + 1];      // prefetch next bound
                    float b2 = fmaf(2.0f*g, r, fmaf(r, r, t2));
                    if (b2 * 1.00001f < thr) break;      // margin: fp-safe skip
                    float dx = q.x - tvx, dy = q.y - tvy, dz = q.z - tvz;
                    float d2 = has ? fmaf(dx, dx, fmaf(dy, dy, dz * dz)) : -1.0f;
                    process_chunk(d2, __float_as_int(q.w), has);
                    r = rn;
                }
            };
            // rest of bootstrap octant first (thr is already near-final)
            float r1 = rmax[ob*nbo + 1];   // in-bounds (padded); unused if no chunk 1
            scan_octant(ob, oS, oE, 1, r1, sqrtf(bg));
            for (int o2 = 0; o2 < 8; ++o2) {
                if (o2 == ob) continue;
                int s2 = __shfl(prefS, o2), e2 = __shfl(prefS, o2 + 1);
                scan_octant(o2, s2, e2, 0, __shfl(prefR0, o2), sqrtf(g2v(o2)));
            }
        } else {
            for (int ib = 64; ib < N; ib += 64) {
                int  i   = ib + lane;
                bool has = (i < N);
                int g = has ? i : 0;
                float dx = sv[3*g] - tvx, dy = sv[3*g+1] - tvy,
                      dz = sv[3*g+2] - tvz;
                float d2 = has ? fmaf(dx, dx, fmaf(dy, dy, dz * dz)) : -1.0f;
                process_chunk(d2, i, has);
            }
        }

        // ---- epilogue: argmin angle, tie-break by top-k rank (= lane) ----
        const float tnx = tn[3*m], tny = tn[3*m+1], tnz = tn[3*m+2];
        float ang = 3.0e38f;
        int myI = eI;
        if (lane < K && myI != 0x7FFFFFFF) {
            float dot = sn[3*myI]*tnx + sn[3*myI+1]*tny + sn[3*myI+2]*tnz;
            dot = fminf(1.0f, fmaxf(-1.0f, dot));
            ang = acosf(dot) * 57.29577951308232f;   // degrees, matches jnp
        }
        float ba = ang; int br = lane; int bi = myI;
#pragma unroll
        for (int s = 1; s < 16; s <<= 1) {
            float oa  = __shfl_xor(ba, s);
            int   orr = __shfl_xor(br, s);
            int   oi  = __shfl_xor(bi, s);
            bool take = (oa < ba) || (oa == ba && orr < br);
            if (take) { ba = oa; br = orr; bi = oi; }
        }
        if (lane == 0) {
            float dx = sv[3*bi]   - tvx;
            float dy = sv[3*bi+1] - tvy;
            float dz = sv[3*bi+2] - tvz;
            contrib = sqrtf(dx*dx + dy*dy + dz*dz) * invM;
        }
    }

    if (lane == 0) bsum[w] = contrib;
    __syncthreads();
    if (threadIdx.x == 0)
        partial[blockIdx.x] = bsum[0] + bsum[1] + bsum[2] + bsum[3];
}

__global__ __launch_bounds__(256) void reduce_kernel(
    const float* __restrict__ partial, float* __restrict__ out, int n)
{
    __shared__ float sh[4];
    const int lane = threadIdx.x & 63;
    const int w    = threadIdx.x >> 6;
    float s = 0.0f;
    for (int i = threadIdx.x; i < n; i += 256) s += partial[i];
#pragma unroll
    for (int d = 1; d < 64; d <<= 1) s += __shfl_xor(s, d);
    if (lane == 0) sh[w] = s;
    __syncthreads();
    if (threadIdx.x == 0) out[0] = sh[0] + sh[1] + sh[2] + sh[3];
}

extern "C" void kernel_launch(void* const* d_in, const int* in_sizes, int n_in,
                              void* d_out, int out_size, void* d_ws, size_t ws_size,
                              hipStream_t stream) {
    const float* sv = (const float*)d_in[0];   // scan_vertices     [1,N,3]
    const float* tv = (const float*)d_in[1];   // template_vertices [1,M,3]
    const float* sn = (const float*)d_in[2];   // scan_normals      [N,3]
    const float* tn = (const float*)d_in[3];   // template_normals  [M,3]
    // d_in[4] = K_knn (fixed 15, compile-time)

    int N = in_sizes[0] / 3;
    int M = in_sizes[1] / 3;
    int nb = (N + 63) / 64;                    // max chunks per octant
    float* out = (float*)d_out;
    float invM = 1.0f / (float)M;
    int grid  = (M + WAVES - 1) / WAVES;
    int nblk  = (N + 255) / 256;

    // d_ws: [sorted N float4][rmax 8*nb+8][octStartG 9][ghist 2048][pb N][partial]
    size_t offSorted  = 0;
    size_t offRmax    = offSorted + (size_t)N * sizeof(float4);
    size_t offOct     = (offRmax + ((size_t)8 * nb + 8) * sizeof(float) + 15) & ~(size_t)15;
    size_t offGhist   = (offOct + 9 * sizeof(int) + 15) & ~(size_t)15;
    size_t offPb      = offGhist + (size_t)NBUCK2 * sizeof(int);
    size_t offPartial = offPb + (size_t)N * sizeof(int);
    size_t need       = offPartial + (size_t)grid * sizeof(float);

    if (ws_size >= need) {
        float4* sorted   = (float4*)((char*)d_ws + offSorted);
        float*  rmaxp    = (float*) ((char*)d_ws + offRmax);
        int*    octStart = (int*)   ((char*)d_ws + offOct);
        int*    ghist    = (int*)   ((char*)d_ws + offGhist);
        int*    pb       = (int*)   ((char*)d_ws + offPb);
        float*  partial  = (float*) ((char*)d_ws + offPartial);

        hipMemsetAsync(ghist, 0, (size_t)NBUCK2 * sizeof(int), stream);
        rank_kernel   <<<nblk, 256, 0, stream>>>(sv, ghist, pb, N);
        scatter_kernel<<<nblk, 256, 0, stream>>>(sv, ghist, pb, sorted,
                                                 rmaxp, octStart, N, nb);
        knn_loss_kernel<true><<<grid, WAVES * 64, 0, stream>>>(
            sorted, rmaxp, octStart, sv, tv, sn, tn, partial, N, M, invM, nb);
        reduce_kernel<<<1, 256, 0, stream>>>(partial, out, grid);
    } else if (ws_size >= (size_t)grid * sizeof(float)) {
        float* partial = (float*)d_ws;
        knn_loss_kernel<false><<<grid, WAVES * 64, 0, stream>>>(
            nullptr, nullptr, nullptr, sv, tv, sn, tn, partial, N, M, invM, nb);
        reduce_kernel<<<1, 256, 0, stream>>>(partial, out, grid);
    }
}